// Round 1
// baseline (106.196 us; speedup 1.0000x reference)
//
#include <hip/hip_runtime.h>
#include <math.h>

// GyroLoss: fused so3_exp / bmtm / so3_log / Huber-mean over (64, 8192) rows.
// Memory-bound: 50.3 MB in, 4 B out. One row per thread, LDS-staged coalesced loads.

namespace {
constexpr int kN = 64;
constexpr int kT = 8192;
constexpr int kN0 = 5;
constexpr int kRows = kN * kT;              // 524288
constexpr int kRowsPerBlock = 256;          // == blockDim.x
// out = W * HUBER^2 * mean = 25 * sum / (64 * 8187 * 15)
constexpr float kScale = (float)(25.0 / ((double)kN * (double)(kT - kN0) * 15.0));
}

// Rodrigues: R = I + A*K + B*K^2, K = skew(x,y,z). Row-major R[9].
__device__ __forceinline__ void so3_exp9(float x, float y, float z, float R[9]) {
    float t2 = x * x + y * y + z * z;
    bool sm = t2 < 1e-8f;
    float st2 = sm ? 1.0f : t2;
    float th = sqrtf(st2);
    float s, c;
    sincosf(th, &s, &c);
    float A = sm ? (1.0f - t2 * (1.0f / 6.0f)) : (s / th);
    float B = sm ? (0.5f - t2 * (1.0f / 24.0f)) : ((1.0f - c) / st2);
    R[0] = 1.0f - B * (y * y + z * z);
    R[1] = B * x * y - A * z;
    R[2] = B * x * z + A * y;
    R[3] = B * x * y + A * z;
    R[4] = 1.0f - B * (x * x + z * z);
    R[5] = B * y * z - A * x;
    R[6] = B * x * z - A * y;
    R[7] = B * y * z + A * x;
    R[8] = 1.0f - B * (x * x + y * y);
}

// out = so3_log(a^T * b); C[i][k] = sum_j a[3j+i] * b[3j+k]
__device__ __forceinline__ void bmtm_log(const float a[9], const float b[9], float out[3]) {
    float C00 = a[0] * b[0] + a[3] * b[3] + a[6] * b[6];
    float C11 = a[1] * b[1] + a[4] * b[4] + a[7] * b[7];
    float C22 = a[2] * b[2] + a[5] * b[5] + a[8] * b[8];
    float C21 = a[2] * b[1] + a[5] * b[4] + a[8] * b[7];
    float C12 = a[1] * b[2] + a[4] * b[5] + a[7] * b[8];
    float C02 = a[0] * b[2] + a[3] * b[5] + a[6] * b[8];
    float C20 = a[2] * b[0] + a[5] * b[3] + a[8] * b[6];
    float C10 = a[1] * b[0] + a[4] * b[3] + a[7] * b[6];
    float C01 = a[0] * b[1] + a[3] * b[4] + a[6] * b[7];
    float tr = C00 + C11 + C22;
    float cs = 0.5f * (tr - 1.0f);
    cs = fminf(1.0f, fmaxf(-1.0f, cs));
    bool sm = cs > (1.0f - 1e-6f);
    float sc = sm ? 0.0f : cs;
    float ang = acosf(sc);
    float factor = sm ? 0.5f : (ang / (2.0f * sinf(ang)));
    out[0] = factor * (C21 - C12);
    out[1] = factor * (C02 - C20);
    out[2] = factor * (C10 - C01);
}

__device__ __forceinline__ float huber_term(float r) {
    float z = r * 200.0f;  // 1/HUBER
    float az = fabsf(z);
    return az < 1.0f ? 0.5f * z * z : az - 0.5f;
}

__global__ __launch_bounds__(256) void gyro_loss_kernel(
    const float* __restrict__ xs, const float* __restrict__ hx,
    float* __restrict__ out) {
    __shared__ float s_xs[kRowsPerBlock * 9];   // 9216 B
    __shared__ float s_hx[kRowsPerBlock * 15];  // 15360 B
    const int tid = threadIdx.x;
    const long base_row = (long)blockIdx.x * kRowsPerBlock;

    // Coalesced staging: consecutive threads -> consecutive addresses.
    const float* gx = xs + base_row * 9;
    const float* gh = hx + base_row * 15;
#pragma unroll
    for (int i = 0; i < 9; ++i) s_xs[tid + i * kRowsPerBlock] = gx[tid + i * kRowsPerBlock];
#pragma unroll
    for (int i = 0; i < 15; ++i) s_hx[tid + i * kRowsPerBlock] = gh[tid + i * kRowsPerBlock];
    __syncthreads();

    const int row = (int)base_row + tid;
    const int t = row & (kT - 1);
    float sum = 0.0f;
    if (t >= kN0) {
        const float* x = s_xs + tid * 9;   // stride 9 (odd) -> <=2-way bank alias, free
        const float* h = s_hx + tid * 15;  // stride 15 (odd) -> free
        float Rw[9], Ro[9], Rx[9];
        so3_exp9(x[0], x[1], x[2], Rw);
        so3_exp9(h[0], h[1], h[2], Ro);
        so3_exp9(h[6], h[7], h[8], Rx);
        float l1[3], l3[3];
        bmtm_log(Rw, Ro, l1);
        bmtm_log(Rw, Rx, l3);
        // rs1 = 6 * log(Omegas^T hat_Omegas)
        sum += huber_term(6.0f * l1[0]) + huber_term(6.0f * l1[1]) + huber_term(6.0f * l1[2]);
        // rs2 = 6 * (dv - hat_acc)
        sum += huber_term(6.0f * (x[3] - h[3])) + huber_term(6.0f * (x[4] - h[4])) +
               huber_term(6.0f * (x[5] - h[5]));
        // rs3 = log(Omegas^T hat_Xi)
        sum += huber_term(l3[0]) + huber_term(l3[1]) + huber_term(l3[2]);
        // rs4 = dv - hat_dv
        sum += huber_term(x[3] - h[9]) + huber_term(x[4] - h[10]) + huber_term(x[5] - h[11]);
        // rs5 = dp - hat_dp
        sum += huber_term(x[6] - h[12]) + huber_term(x[7] - h[13]) + huber_term(x[8] - h[14]);
    }

    // wave64 butterfly reduce
#pragma unroll
    for (int off = 32; off > 0; off >>= 1) sum += __shfl_down(sum, off, 64);
    __shared__ float wsum[4];
    const int lane = tid & 63;
    const int w = tid >> 6;
    if (lane == 0) wsum[w] = sum;
    __syncthreads();
    if (tid == 0) {
        float tot = (wsum[0] + wsum[1] + wsum[2] + wsum[3]) * kScale;
        atomicAdd(out, tot);
    }
}

extern "C" void kernel_launch(void* const* d_in, const int* in_sizes, int n_in,
                              void* d_out, int out_size, void* d_ws, size_t ws_size,
                              hipStream_t stream) {
    const float* xs = (const float*)d_in[0];
    const float* hx = (const float*)d_in[1];
    float* out = (float*)d_out;
    // d_out is poisoned to 0xAA before every timed launch -> zero it on-stream.
    hipMemsetAsync(out, 0, sizeof(float), stream);
    gyro_loss_kernel<<<kRows / kRowsPerBlock, kRowsPerBlock, 0, stream>>>(xs, hx, out);
}